// Round 8
// baseline (625.815 us; speedup 1.0000x reference)
//
#include <hip/hip_runtime.h>
#include <hip/hip_bf16.h>

// CensorNet T=512,B=256,I=128,H=256 GRU scan + BCE decode.
// R12: two dispatches per chunk. gemm3 = single-tile-per-block gi GEMM
// (grid 6 x tc*2, 256 thr) reading x AND Wih directly as fp32 with
// in-register RNE bf16 casts (identical values to the old xconv/prep paths),
// plus prep's side work folded in (Whh/Wdec quantize grid-strided; h_ws/out
// zero under `first` flag). Deletes xconv's 100MB round-trip + 2 dispatch
// boundaries. rec_kernel byte-identical to R8/R11 (357us, at its structural
// floor: 1679 cyc/step = ~980 MFMA issue + ~500 VALU + ~200 LDS/barrier;
// MfmaUtil+VALUBusy ~95% of active-CU cycles).
// Ledger: R6 (fence thrash), R9 (serialized fusion), R10 (VGPR spill) --
// producer-consumer / GEMM-into-scan family closed.

typedef __bf16 bf16x8_t __attribute__((ext_vector_type(8)));
typedef float floatx4_t __attribute__((ext_vector_type(4)));
typedef int intx4_t __attribute__((ext_vector_type(4)));
typedef unsigned int u32;
typedef u32 u32x4_t __attribute__((ext_vector_type(4)));

#define SW 2032.0f
#define SH 127.0f
#define INV_S (1.0f / (127.0f * 2032.0f))
#define NL2E (-1.44269504088896f) /* -log2(e) */
#define CRZ (NL2E * INV_S)
#define CN (2.0f * NL2E * INV_S)

static __device__ inline u32 pack2bf(float a, float b) {
  __bf16 x = (__bf16)a, y = (__bf16)b;
  unsigned short ux = *(unsigned short*)&x, uy = *(unsigned short*)&y;
  return (u32)ux | ((u32)uy << 16);
}

static __device__ inline bf16x8_t cvt8(const float* __restrict__ p) {
  floatx4_t a = *(const floatx4_t*)p;
  floatx4_t b = *(const floatx4_t*)(p + 4);
  bf16x8_t t;
#pragma unroll
  for (int j = 0; j < 4; ++j) {
    t[j] = (__bf16)a[j];
    t[4 + j] = (__bf16)b[j];
  }
  return t;
}

// ---------------- gemm3: fp32-direct gi GEMM + folded prep ----------------
// gi layout (dword = bf16 pair for cols ss=0/ss=1, 16 apart):
//   U = (((t*64 + gg)*3 + gate)*8 + wrec)*64 + jb*16 + q*4 (+j)
// Pre-scaling: r,z: NL2E*(gi+bih+bhh); n: 2*NL2E*(gi+bih).
// Block: bx = n-tile (0..5, gate = bx>>1); by = b-tile (ts = by>>1).
__global__ __launch_bounds__(256, 2) void gemm3_kernel(
    const float* __restrict__ x,     // chunk base [tc*256][128] fp32
    const float* __restrict__ Wih,   // [768][128] fp32
    const float* __restrict__ bih, const float* __restrict__ bhh,
    const float* __restrict__ Whh,   // [768][256] fp32
    const float* __restrict__ Wdec,  // [256] fp32
    char* __restrict__ Wq, char* __restrict__ wdq,
    float* __restrict__ h_ws, u32* __restrict__ giw,
    float* __restrict__ out, int first) {
  const int tid = threadIdx.x;
  const int w = tid >> 6, lane = tid & 63;
  const int q = lane >> 4, nh = lane & 15;
  const int n0 = blockIdx.x * 128;
  const int wm = w >> 1, wn = w & 1;
  const int flat = blockIdx.y * 6 + blockIdx.x;
  const int nthr = gridDim.y * 6 * 256;

  // ---- folded prep: quantize Whh/Wdec; zero h_ws/out on first chunk ----
  for (int i = flat * 256 + tid; i < 768 * 256; i += nthr) {
    int v = (int)rintf(Whh[i] * SW);
    v = v > 127 ? 127 : (v < -127 ? -127 : v);
    Wq[i] = (char)v;
  }
  if (flat == 0) {
    int v = (int)rintf(Wdec[tid] * SW);
    v = v > 127 ? 127 : (v < -127 ? -127 : v);
    wdq[tid] = (char)v;
  }
  if (first) {
    for (int i = flat * 256 + tid; i < 65536; i += nthr) h_ws[i] = 0.f;
    if (flat == 0 && tid == 0) out[0] = 0.f;
  }

  // ---- Wih fragments: fp32 load + in-register bf16 cast (RNE, same values
  // as the old prep Wihb path) ----
  bf16x8_t af[4][4];
#pragma unroll
  for (int mt = 0; mt < 4; ++mt)
#pragma unroll
    for (int kk = 0; kk < 4; ++kk)
      af[mt][kk] = cvt8(Wih + (size_t)(n0 + wm * 64 + mt * 16 + nh) * 128 +
                        kk * 32 + q * 8);

  // epilogue constants
  const int gate = n0 >> 8;
  const float sc = (gate < 2) ? NL2E : (2.0f * NL2E);
  const int wr_base = ((n0 & 255) >> 5) + wm * 2;
  floatx4_t biasA[2], biasB[2];
#pragma unroll
  for (int a = 0; a < 2; ++a) {
    const int nnA = n0 + wm * 64 + a * 32 + q * 4;
    biasA[a] = *(const floatx4_t*)(bih + nnA);
    biasB[a] = *(const floatx4_t*)(bih + nnA + 16);
    if (gate < 2) {
      floatx4_t c1 = *(const floatx4_t*)(bhh + nnA);
      floatx4_t c2 = *(const floatx4_t*)(bhh + nnA + 16);
#pragma unroll
      for (int j = 0; j < 4; ++j) {
        biasA[a][j] += c1[j];
        biasB[a][j] += c2[j];
      }
    }
  }

  const int ts = blockIdx.y >> 1;
  const int b0 = (blockIdx.y & 1) * 128;

  floatx4_t acc[4][4];
#pragma unroll
  for (int a = 0; a < 4; ++a)
#pragma unroll
    for (int b = 0; b < 4; ++b)
#pragma unroll
      for (int j = 0; j < 4; ++j) acc[a][b][j] = 0.f;

#pragma unroll
  for (int kk = 0; kk < 4; ++kk) {
    bf16x8_t bf[4];
#pragma unroll
    for (int nt = 0; nt < 4; ++nt)
      bf[nt] = cvt8(x + (size_t)(ts * 256 + b0 + wn * 64 + nt * 16 + nh) * 128 +
                    kk * 32 + q * 8);
#pragma unroll
    for (int mt = 0; mt < 4; ++mt)
#pragma unroll
      for (int nt = 0; nt < 4; ++nt)
        acc[mt][nt] = __builtin_amdgcn_mfma_f32_16x16x32_bf16(
            af[mt][kk], bf[nt], acc[mt][nt], 0, 0, 0);
  }

  // epilogue: verbatim expressions from gemm1/gemm2
#pragma unroll
  for (int a = 0; a < 2; ++a) {
    const int wrec = wr_base + a;
#pragma unroll
    for (int nt = 0; nt < 4; ++nt) {
      const int bb = b0 + wn * 64 + nt * 16 + nh;  // 0..255 within step
      const int gg = bb >> 2, jb = bb & 3;
      size_t U = (((size_t)ts * 64 + gg) * 3 + gate) * 512 + wrec * 64 +
                 jb * 16 + q * 4;
      u32x4_t pv;
#pragma unroll
      for (int j = 0; j < 4; ++j)
        pv[j] = pack2bf((acc[2 * a][nt][j] + biasA[a][j]) * sc,
                        (acc[2 * a + 1][nt][j] + biasB[a][j]) * sc);
      *(u32x4_t*)(giw + U) = pv;
    }
  }
}

// ---------------- rec: serial scan, 16 waves, replicated-A i8 MFMA --------
// (byte-identical to R8/R11; 357us, MfmaUtil 11.8%, bank conflicts 0)
__global__ __launch_bounds__(1024) void rec_kernel(
    const char* __restrict__ Wq,   // [768][256] i8
    const char* __restrict__ wdq,  // [256] i8
    const u32* __restrict__ gi,    // pre-scaled bf16-pair units
    const float* __restrict__ gt, const float* __restrict__ bdec,
    const float* __restrict__ bhh, float* __restrict__ h_ws,
    float* __restrict__ out, int t0, int tc) {
  __shared__ char hb[2][4][288];  // h i8 ping-pong; stride 288 (2-way free)
  __shared__ float lp[4][2048];   // decoder partials (kb 0..3), exact ints

  const int tid = threadIdx.x;
  const int w = tid >> 6, lane = tid & 63;  // wave 0..15
  const int q = lane >> 4, nh = lane & 15;  // q = batch row 0..3
  const int g = blockIdx.x;                 // batch slice 0..63 (4 rows)
  const int col = w * 16 + nh;              // this lane's single h col
  const int wp = w >> 1;                    // gi dword group
  const int hi = w & 1;                     // lo/hi bf16 half (wave-uniform)

  // W_hh fragments (i8, B-operand): wave owns cols w*16..+15 for 3 gates
  intx4_t wf[3][4];
#pragma unroll
  for (int c = 0; c < 3; ++c) {
    const int n = c * 256 + col;
#pragma unroll
    for (int kb = 0; kb < 4; ++kb)
      wf[c][kb] = *(const intx4_t*)(Wq + (size_t)n * 256 + kb * 64 + q * 16);
  }
  // Wdec fragment: wave 12+kb owns k-block kb (one per SIMD)
  intx4_t wdfk;
  {
    const int kb = (w >= 12) ? (w - 12) : 0;
    intx4_t z = {0, 0, 0, 0};
    intx4_t v = *(const intx4_t*)(wdq + kb * 64 + q * 16);
    wdfk = (nh == 0) ? v : z;  // B col 0 = Wdec
  }

  const float bn2 = 2.0f * NL2E * bhh[512 + col];
  const float bdec0 = bdec[0];

  // stage initial h rows 0..3 quantized (256 words)
  if (tid < 256) {
    const int rr = tid >> 6, c0 = (tid & 63) * 4;
    u32 p = 0;
#pragma unroll
    for (int j = 0; j < 4; ++j) {
      int a = (int)rintf(h_ws[(size_t)(g * 4 + rr) * 256 + c0 + j] * SH);
      a = a > 127 ? 127 : (a < -127 ? -127 : a);
      p |= ((u32)(a & 255)) << (8 * j);
    }
    *(u32*)&hb[0][rr][c0] = p;
  }
  float ho = h_ws[(size_t)(g * 4 + q) * 256 + col];
  __syncthreads();

  const int tcm1 = tc - 1;
  const size_t boff = (size_t)wp * 64 + q * 16 + nh;
  // depth-2 prefetch register sets
  u32 GA[3], GB[3];
  {
    size_t u0 = ((size_t)g * 3) * 512 + boff;
#pragma unroll
    for (int c = 0; c < 3; ++c) GA[c] = gi[u0 + c * 512];
    const int t1s = tc > 1 ? 1 : 0;
    size_t u1 = (((size_t)t1s * 64 + g) * 3) * 512 + boff;
#pragma unroll
    for (int c = 0; c < 3; ++c) GB[c] = gi[u1 + c * 512];
  }

  // one GRU step: consumes G (gi of step T), then refills G from step TPRE
  auto STEP = [&](int T, u32* G, int TPRE) {
    const int pb = T & 1;
    intx4_t hbf[4];  // A-operand: row m holds h[m>>2] (4-lane broadcast)
#pragma unroll
    for (int kb = 0; kb < 4; ++kb)
      hbf[kb] = *(const intx4_t*)&hb[pb][nh >> 2][kb * 64 + q * 16];

    // extract old G (issued ~2 steps ago), then refill for step T+2
    float gv0, gv1, gv2;
    if (hi) {
      gv0 = __uint_as_float(G[0] & 0xffff0000u);
      gv1 = __uint_as_float(G[1] & 0xffff0000u);
      gv2 = __uint_as_float(G[2] & 0xffff0000u);
    } else {
      gv0 = __uint_as_float(G[0] << 16);
      gv1 = __uint_as_float(G[1] << 16);
      gv2 = __uint_as_float(G[2] << 16);
    }
    {
      size_t up = (((size_t)TPRE * 64 + g) * 3) * 512 + boff;
#pragma unroll
      for (int c = 0; c < 3; ++c) G[c] = gi[up + c * 512];
    }

    intx4_t acc[3];
#pragma unroll
    for (int cs = 0; cs < 3; ++cs)
#pragma unroll
      for (int jj = 0; jj < 4; ++jj) acc[cs][jj] = 0;

#pragma unroll
    for (int kb = 0; kb < 4; ++kb)
#pragma unroll
      for (int cs = 0; cs < 3; ++cs)
        acc[cs] = __builtin_amdgcn_mfma_i32_16x16x64_i8(hbf[kb], wf[cs][kb],
                                                        acc[cs], 0, 0, 0);
    // acc[cs][0] = gh[batch q][col] for gate cs -- in-register.

    // decoder partial: waves 12..15, one k-block each (one per SIMD)
    if (w >= 12) {
      intx4_t hsel = (w == 12) ? hbf[0]
                   : (w == 13) ? hbf[1]
                   : (w == 14) ? hbf[2] : hbf[3];
      intx4_t facc = {0, 0, 0, 0};
      facc = __builtin_amdgcn_mfma_i32_16x16x64_i8(hsel, wdfk, facc, 0, 0, 0);
      if (nh == 0 && T >= 1) lp[w - 12][(T - 1) * 4 + q] = (float)facc[0];
    }

    float rr0 = __builtin_amdgcn_rcpf(
        1.f + __builtin_amdgcn_exp2f((float)acc[0][0] * CRZ + gv0));
    float zz0 = __builtin_amdgcn_rcpf(
        1.f + __builtin_amdgcn_exp2f((float)acc[1][0] * CRZ + gv1));
    float hn2 = (float)acc[2][0] * CN + bn2;
    float tv0 = 2.f * __builtin_amdgcn_rcpf(
                          1.f + __builtin_amdgcn_exp2f(rr0 * hn2 + gv2)) -
                1.f;
    float hnew = tv0 + zz0 * (ho - tv0);
    ho = hnew;
    int h8 = (int)rintf(hnew * SH);
    hb[1 - pb][q][col] = (char)h8;

    // light barrier: drain LDS only; gi prefetch stays in flight
    asm volatile("s_waitcnt lgkmcnt(0)" ::: "memory");
    __builtin_amdgcn_s_barrier();
    asm volatile("" ::: "memory");
  };

  int t = 0;
#pragma unroll 1
  for (; t + 1 < tc; t += 2) {
    STEP(t, GA, (t + 2 <= tcm1) ? t + 2 : tcm1);
    STEP(t + 1, GB, (t + 3 <= tcm1) ? t + 3 : tcm1);
  }
  if (t < tc) STEP(t, GA, tcm1);

  // tail: decoder partials of final state
  if (w >= 12) {
    const int kb = w - 12;
    intx4_t b = *(const intx4_t*)&hb[tc & 1][nh >> 2][kb * 64 + q * 16];
    intx4_t fac2 = {0, 0, 0, 0};
    fac2 = __builtin_amdgcn_mfma_i32_16x16x64_i8(b, wdfk, fac2, 0, 0, 0);
    if (nh == 0) lp[kb][(tc - 1) * 4 + q] = (float)fac2[0];
  }
  __syncthreads();

  // bulk BCE sweep (partial sums are exact: each < 2^20, sum < 2^23)
  float loss = 0.f;
  for (int i = tid; i < tc * 4; i += 1024) {
    float l = (lp[0][i] + lp[1][i] + lp[2][i] + lp[3][i]) * INV_S + bdec0;
    float gtv = gt[(size_t)(t0 + (i >> 2) + 1) * 256 + g * 4 + (i & 3)];
    float t1 = log1pf(__expf(-fabsf(l)));
    loss += gtv * (fmaxf(-l, 0.f) + t1) + (1.f - gtv) * (fmaxf(l, 0.f) + t1);
  }
  loss += __shfl_xor(loss, 1);
  loss += __shfl_xor(loss, 2);
  loss += __shfl_xor(loss, 4);
  loss += __shfl_xor(loss, 8);
  loss += __shfl_xor(loss, 16);
  loss += __shfl_xor(loss, 32);
  if (lane == 0) atomicAdd(out, loss);

  // persist h (fp32) for next chunk
  h_ws[(size_t)(g * 4 + q) * 256 + col] = ho;
}

// ---------------- host ----------------
extern "C" void kernel_launch(void* const* d_in, const int* in_sizes, int n_in,
                              void* d_out, int out_size, void* d_ws,
                              size_t ws_size, hipStream_t stream) {
  const float* x = (const float*)d_in[0];     // [512,256,128]
  const float* gt = (const float*)d_in[1];    // [512,256,1]
  const float* Wih = (const float*)d_in[2];   // [768,128]
  const float* Whh = (const float*)d_in[3];   // [768,256]
  const float* bih = (const float*)d_in[4];   // [768]
  const float* bhh = (const float*)d_in[5];   // [768]
  const float* Wdec = (const float*)d_in[6];  // [1,256]
  const float* bdec = (const float*)d_in[7];  // [1]
  float* out = (float*)d_out;

  char* ws = (char*)d_ws;
  char* Wq = ws;                        // 196608 B
  char* wdq = ws + 196608;              // 512 B (256 used)
  float* h_ws = (float*)(ws + 197120);  // 262144 B
  char* dyn = ws + 459264;
  const size_t per_step = (size_t)393216;  // gi per time step
  size_t avail = ws_size > 459264 ? ws_size - 459264 : per_step;
  int Tc = (int)(avail / per_step);
  if (Tc < 1) Tc = 1;
  if (Tc > 511) Tc = 511;
  u32* gi = (u32*)dyn;  // Tc*393216 B

  for (int t0 = 0; t0 < 511; t0 += Tc) {
    const int tc = (511 - t0 < Tc) ? (511 - t0) : Tc;
    gemm3_kernel<<<dim3(6, tc * 2), 256, 0, stream>>>(
        x + (size_t)t0 * 256 * 128, Wih, bih, bhh, Whh, Wdec, Wq, wdq, h_ws,
        gi, out, t0 == 0 ? 1 : 0);
    rec_kernel<<<64, 1024, 0, stream>>>(Wq, wdq, gi, gt, bdec, bhh, h_ws, out,
                                        t0, tc);
  }
}

// Round 10
// 521.849 us; speedup vs baseline: 1.1992x; 1.1992x over previous
//
#include <hip/hip_runtime.h>
#include <hip/hip_bf16.h>

// CensorNet T=512,B=256,I=128,H=256 GRU scan + BCE decode.
// R13 (resubmit; prior bench died to infra "container failed twice", source
// re-audited: gi pad bounds, xconv grid arithmetic, no sync/spin hazards).
// R8 structure restored exactly (xconv bf16 pre-pass + LDS-tile gemm1;
// R12's fp32-direct gemm read 392MB scattered fp32 -> closed). Changes:
//  (1) prep folded into xconv (grid-stride side work; one less dispatch).
//  (2) rec VALU diet: persistent zero C-operand for all MFMAs (kills 16
//      v_mov zero-inits/wave/step); gi padded +2 steps so the depth-2
//      prefetch needs no TPRE clamp -- per-lane pointers advance by a
//      constant (2 inst) and the 3 gate loads fold into imm offsets
//      0/2048/4096. Dead pad prefetches are never extracted -> trajectory
//      bit-identical; absmax 0.0 expected.
// Ledger: R6 fence-thrash, R9 serialized fusion, R10 VGPR spill, R12
// fp32-direct -- structural pre-phase reworks closed.

typedef __bf16 bf16x8_t __attribute__((ext_vector_type(8)));
typedef float floatx4_t __attribute__((ext_vector_type(4)));
typedef int intx4_t __attribute__((ext_vector_type(4)));
typedef unsigned int u32;
typedef u32 u32x4_t __attribute__((ext_vector_type(4)));

#define SW 2032.0f
#define SH 127.0f
#define INV_S (1.0f / (127.0f * 2032.0f))
#define NL2E (-1.44269504088896f) /* -log2(e) */
#define CRZ (NL2E * INV_S)
#define CN (2.0f * NL2E * INV_S)

static __device__ inline u32 pack2bf(float a, float b) {
  __bf16 x = (__bf16)a, y = (__bf16)b;
  unsigned short ux = *(unsigned short*)&x, uy = *(unsigned short*)&y;
  return (u32)ux | ((u32)uy << 16);
}

// ---------------- xconv: x chunk fp32->bf16 + folded prep -----------------
__global__ __launch_bounds__(256) void xconv_kernel(
    const float* __restrict__ x, __bf16* __restrict__ xb,
    const float* __restrict__ Whh, const float* __restrict__ Wdec,
    const float* __restrict__ Wih, char* __restrict__ Wq,
    char* __restrict__ wdq, __bf16* __restrict__ Wihb,
    float* __restrict__ h_ws, float* __restrict__ out, int first) {
  const int flat = blockIdx.x * 256 + threadIdx.x;
  const int nthr = gridDim.x * 256;

  // main: bf16 conversion of the x chunk
  const size_t i = (size_t)flat * 8;
  floatx4_t a = *(const floatx4_t*)(x + i);
  floatx4_t b = *(const floatx4_t*)(x + i + 4);
  bf16x8_t t;
#pragma unroll
  for (int j = 0; j < 4; ++j) {
    t[j] = (__bf16)a[j];
    t[4 + j] = (__bf16)b[j];
  }
  *(bf16x8_t*)(xb + i) = t;

  // folded prep (grid-stride; idempotent across chunks)
  for (int k = flat; k < 768 * 256; k += nthr) {
    int v = (int)rintf(Whh[k] * SW);
    v = v > 127 ? 127 : (v < -127 ? -127 : v);
    Wq[k] = (char)v;
  }
  for (int k = flat; k < 768 * 128; k += nthr) Wihb[k] = (__bf16)Wih[k];
  if (flat < 256) {
    int v = (int)rintf(Wdec[flat] * SW);
    v = v > 127 ? 127 : (v < -127 ? -127 : v);
    wdq[flat] = (char)v;
  }
  if (first) {
    for (int k = flat; k < 65536; k += nthr) h_ws[k] = 0.f;
    if (flat == 0) out[0] = 0.f;
  }
}

// ---------------- gemm1: gi = scale * (x @ W_ih.T + biases) ---------------
// (byte-identical to R8's gemm1 -- the 518us config)
// gi layout (dword = bf16 pair for cols ss=0/ss=1, 16 apart):
//   U = (((t*64 + g)*3 + gate)*8 + wrec)*64 + jb*16 + nh_rec
// Pre-scaling: r,z: NL2E*(gi+bih+bhh); n: 2*NL2E*(gi+bih).
__global__ __launch_bounds__(256) void gemm1_kernel(
    const __bf16* __restrict__ xb,    // [tc*256][128] bf16
    const __bf16* __restrict__ Wihb,  // [768][128] bf16
    const float* __restrict__ bih, const float* __restrict__ bhh,
    u32* __restrict__ giw) {
  __shared__ __bf16 As[128][144];  // Wih tile, rows n
  __shared__ __bf16 Bs[128][144];  // x tile, rows b

  const int tid = threadIdx.x;
  const int w = tid >> 6, lane = tid & 63;
  const int q = lane >> 4, nh = lane & 15;
  const int n0 = blockIdx.x * 128;
  const int b0 = blockIdx.y * 128;
  const int wm = w >> 1, wn = w & 1;

  {
    const bf16x8_t* sa = (const bf16x8_t*)(Wihb + (size_t)n0 * 128);
    const bf16x8_t* sb = (const bf16x8_t*)(xb + (size_t)b0 * 128);
    const int rr = tid >> 4, cc = (tid & 15) * 8;
#pragma unroll
    for (int v = 0; v < 8; ++v) {
      *(bf16x8_t*)&As[v * 16 + rr][cc] = sa[v * 256 + tid];
      *(bf16x8_t*)&Bs[v * 16 + rr][cc] = sb[v * 256 + tid];
    }
  }
  __syncthreads();

  floatx4_t acc[4][4];
#pragma unroll
  for (int a = 0; a < 4; ++a)
#pragma unroll
    for (int b = 0; b < 4; ++b)
#pragma unroll
      for (int j = 0; j < 4; ++j) acc[a][b][j] = 0.f;

#pragma unroll
  for (int kk = 0; kk < 4; ++kk) {
    bf16x8_t af[4], bf[4];
#pragma unroll
    for (int mt = 0; mt < 4; ++mt)
      af[mt] = *(const bf16x8_t*)&As[wm * 64 + mt * 16 + nh][kk * 32 + q * 8];
#pragma unroll
    for (int nt = 0; nt < 4; ++nt)
      bf[nt] = *(const bf16x8_t*)&Bs[wn * 64 + nt * 16 + nh][kk * 32 + q * 8];
#pragma unroll
    for (int mt = 0; mt < 4; ++mt)
#pragma unroll
      for (int nt = 0; nt < 4; ++nt)
        acc[mt][nt] = __builtin_amdgcn_mfma_f32_16x16x32_bf16(
            af[mt], bf[nt], acc[mt][nt], 0, 0, 0);
  }

  const int gate = n0 >> 8;
  const float sc = (gate < 2) ? NL2E : (2.0f * NL2E);
  const int wr_base = ((n0 & 255) >> 5) + wm * 2;
#pragma unroll
  for (int a = 0; a < 2; ++a) {
    const int nnA = n0 + wm * 64 + a * 32 + q * 4;
    floatx4_t biasA = *(const floatx4_t*)(bih + nnA);
    floatx4_t biasB = *(const floatx4_t*)(bih + nnA + 16);
    if (gate < 2) {
      floatx4_t c1 = *(const floatx4_t*)(bhh + nnA);
      floatx4_t c2 = *(const floatx4_t*)(bhh + nnA + 16);
#pragma unroll
      for (int j = 0; j < 4; ++j) {
        biasA[j] += c1[j];
        biasB[j] += c2[j];
      }
    }
    const int wrec = wr_base + a;
#pragma unroll
    for (int nt = 0; nt < 4; ++nt) {
      const int bb = b0 + wn * 64 + nt * 16 + nh;
      const int tl = bb >> 8, gg = (bb >> 2) & 63, jb = bb & 3;
      size_t U =
          (((size_t)tl * 64 + gg) * 3 + gate) * 512 + wrec * 64 + jb * 16 + q * 4;
      u32x4_t pv;
#pragma unroll
      for (int j = 0; j < 4; ++j)
        pv[j] = pack2bf((acc[2 * a][nt][j] + biasA[j]) * sc,
                        (acc[2 * a + 1][nt][j] + biasB[j]) * sc);
      *(u32x4_t*)(giw + U) = pv;
    }
  }
}

// ---------------- rec: serial scan, 16 waves, replicated-A i8 MFMA --------
// R8 + VALU diet: persistent zero-C MFMAs; pointer-incremental depth-2 gi
// prefetch (gi padded +2 steps; no clamp). Trajectory bit-identical to R8.
__global__ __launch_bounds__(1024) void rec_kernel(
    const char* __restrict__ Wq,   // [768][256] i8
    const char* __restrict__ wdq,  // [256] i8
    const u32* __restrict__ gi,    // pre-scaled bf16-pair units (+2 pad steps)
    const float* __restrict__ gt, const float* __restrict__ bdec,
    const float* __restrict__ bhh, float* __restrict__ h_ws,
    float* __restrict__ out, int t0, int tc) {
  __shared__ char hb[2][4][288];  // h i8 ping-pong; stride 288 (2-way free)
  __shared__ float lp[4][2048];   // decoder partials (kb 0..3), exact ints

  const int tid = threadIdx.x;
  const int w = tid >> 6, lane = tid & 63;  // wave 0..15
  const int q = lane >> 4, nh = lane & 15;  // q = batch row 0..3
  const int g = blockIdx.x;                 // batch slice 0..63 (4 rows)
  const int col = w * 16 + nh;              // this lane's single h col
  const int wp = w >> 1;                    // gi dword group
  const int hi = w & 1;                     // lo/hi bf16 half (wave-uniform)

  // W_hh fragments (i8, B-operand): wave owns cols w*16..+15 for 3 gates
  intx4_t wf[3][4];
#pragma unroll
  for (int c = 0; c < 3; ++c) {
    const int n = c * 256 + col;
#pragma unroll
    for (int kb = 0; kb < 4; ++kb)
      wf[c][kb] = *(const intx4_t*)(Wq + (size_t)n * 256 + kb * 64 + q * 16);
  }
  // Wdec fragment: wave 12+kb owns k-block kb (one per SIMD)
  intx4_t wdfk;
  {
    const int kb = (w >= 12) ? (w - 12) : 0;
    intx4_t z = {0, 0, 0, 0};
    intx4_t v = *(const intx4_t*)(wdq + kb * 64 + q * 16);
    wdfk = (nh == 0) ? v : z;  // B col 0 = Wdec
  }
  const intx4_t ZV = {0, 0, 0, 0};  // persistent MFMA C-operand

  const float bn2 = 2.0f * NL2E * bhh[512 + col];
  const float bdec0 = bdec[0];

  // stage initial h rows 0..3 quantized (256 words)
  if (tid < 256) {
    const int rr = tid >> 6, c0 = (tid & 63) * 4;
    u32 p = 0;
#pragma unroll
    for (int j = 0; j < 4; ++j) {
      int a = (int)rintf(h_ws[(size_t)(g * 4 + rr) * 256 + c0 + j] * SH);
      a = a > 127 ? 127 : (a < -127 ? -127 : a);
      p |= ((u32)(a & 255)) << (8 * j);
    }
    *(u32*)&hb[0][rr][c0] = p;
  }
  float ho = h_ws[(size_t)(g * 4 + q) * 256 + col];
  __syncthreads();

  // depth-2 prefetch: per-lane pointers advance by a 2-step constant;
  // gate loads at imm offsets 0/2048/4096 B (c*512 dwords).
  const size_t base = (size_t)g * 1536 + (size_t)wp * 64 + q * 16 + nh;
  u32 GA[3], GB[3];
  {
    const u32* p0 = gi + base;
    GA[0] = p0[0]; GA[1] = p0[512]; GA[2] = p0[1024];
    const u32* p1 = gi + base + 98304;
    GB[0] = p1[0]; GB[1] = p1[512]; GB[2] = p1[1024];
  }
  const u32* pA = gi + base + 2 * (size_t)98304;
  const u32* pB = gi + base + 3 * (size_t)98304;

  // one GRU step: consumes G (gi of step T); refills G from *P (step T+2,
  // possibly pad garbage for T+2 >= tc -- never extracted); P += 2 steps.
  auto STEP = [&](int T, u32* G, const u32*& P) {
    const int pb = T & 1;
    intx4_t hbf[4];  // A-operand: row m holds h[m>>2] (4-lane broadcast)
#pragma unroll
    for (int kb = 0; kb < 4; ++kb)
      hbf[kb] = *(const intx4_t*)&hb[pb][nh >> 2][kb * 64 + q * 16];

    // extract old G (issued ~2 steps ago), then refill for step T+2
    float gv0, gv1, gv2;
    if (hi) {
      gv0 = __uint_as_float(G[0] & 0xffff0000u);
      gv1 = __uint_as_float(G[1] & 0xffff0000u);
      gv2 = __uint_as_float(G[2] & 0xffff0000u);
    } else {
      gv0 = __uint_as_float(G[0] << 16);
      gv1 = __uint_as_float(G[1] << 16);
      gv2 = __uint_as_float(G[2] << 16);
    }
    G[0] = P[0];
    G[1] = P[512];
    G[2] = P[1024];
    P += 2 * 98304;

    intx4_t a0 = __builtin_amdgcn_mfma_i32_16x16x64_i8(hbf[0], wf[0][0], ZV,
                                                       0, 0, 0);
    intx4_t a1 = __builtin_amdgcn_mfma_i32_16x16x64_i8(hbf[0], wf[1][0], ZV,
                                                       0, 0, 0);
    intx4_t a2 = __builtin_amdgcn_mfma_i32_16x16x64_i8(hbf[0], wf[2][0], ZV,
                                                       0, 0, 0);
#pragma unroll
    for (int kb = 1; kb < 4; ++kb) {
      a0 = __builtin_amdgcn_mfma_i32_16x16x64_i8(hbf[kb], wf[0][kb], a0, 0, 0,
                                                 0);
      a1 = __builtin_amdgcn_mfma_i32_16x16x64_i8(hbf[kb], wf[1][kb], a1, 0, 0,
                                                 0);
      a2 = __builtin_amdgcn_mfma_i32_16x16x64_i8(hbf[kb], wf[2][kb], a2, 0, 0,
                                                 0);
    }
    // a{0,1,2}[0] = gh[batch q][col] for gates r,z,n -- in-register.

    // decoder partial: waves 12..15, one k-block each (one per SIMD)
    if (w >= 12) {
      intx4_t hsel = (w == 12)   ? hbf[0]
                     : (w == 13) ? hbf[1]
                     : (w == 14) ? hbf[2]
                                 : hbf[3];
      intx4_t facc =
          __builtin_amdgcn_mfma_i32_16x16x64_i8(hsel, wdfk, ZV, 0, 0, 0);
      if (nh == 0 && T >= 1) lp[w - 12][(T - 1) * 4 + q] = (float)facc[0];
    }

    float rr0 = __builtin_amdgcn_rcpf(
        1.f + __builtin_amdgcn_exp2f((float)a0[0] * CRZ + gv0));
    float zz0 = __builtin_amdgcn_rcpf(
        1.f + __builtin_amdgcn_exp2f((float)a1[0] * CRZ + gv1));
    float hn2 = (float)a2[0] * CN + bn2;
    float tv0 = 2.f * __builtin_amdgcn_rcpf(
                          1.f + __builtin_amdgcn_exp2f(rr0 * hn2 + gv2)) -
                1.f;
    float hnew = tv0 + zz0 * (ho - tv0);
    ho = hnew;
    int h8 = (int)rintf(hnew * SH);
    hb[1 - pb][q][col] = (char)h8;

    // light barrier: drain LDS only; gi prefetch stays in flight
    asm volatile("s_waitcnt lgkmcnt(0)" ::: "memory");
    __builtin_amdgcn_s_barrier();
    asm volatile("" ::: "memory");
  };

  int t = 0;
#pragma unroll 1
  for (; t + 1 < tc; t += 2) {
    STEP(t, GA, pA);
    STEP(t + 1, GB, pB);
  }
  if (t < tc) STEP(t, GA, pA);

  // tail: decoder partials of final state
  if (w >= 12) {
    const int kb = w - 12;
    intx4_t b = *(const intx4_t*)&hb[tc & 1][nh >> 2][kb * 64 + q * 16];
    intx4_t fac2 =
        __builtin_amdgcn_mfma_i32_16x16x64_i8(b, wdfk, ZV, 0, 0, 0);
    if (nh == 0) lp[kb][(tc - 1) * 4 + q] = (float)fac2[0];
  }
  __syncthreads();

  // bulk BCE sweep (partial sums are exact: each < 2^20, sum < 2^23)
  float loss = 0.f;
  for (int i = tid; i < tc * 4; i += 1024) {
    float l = (lp[0][i] + lp[1][i] + lp[2][i] + lp[3][i]) * INV_S + bdec0;
    float gtv = gt[(size_t)(t0 + (i >> 2) + 1) * 256 + g * 4 + (i & 3)];
    float t1 = log1pf(__expf(-fabsf(l)));
    loss += gtv * (fmaxf(-l, 0.f) + t1) + (1.f - gtv) * (fmaxf(l, 0.f) + t1);
  }
  loss += __shfl_xor(loss, 1);
  loss += __shfl_xor(loss, 2);
  loss += __shfl_xor(loss, 4);
  loss += __shfl_xor(loss, 8);
  loss += __shfl_xor(loss, 16);
  loss += __shfl_xor(loss, 32);
  if (lane == 0) atomicAdd(out, loss);

  // persist h (fp32) for next chunk
  h_ws[(size_t)(g * 4 + q) * 256 + col] = ho;
}

// ---------------- host ----------------
extern "C" void kernel_launch(void* const* d_in, const int* in_sizes, int n_in,
                              void* d_out, int out_size, void* d_ws,
                              size_t ws_size, hipStream_t stream) {
  const float* x = (const float*)d_in[0];     // [512,256,128]
  const float* gt = (const float*)d_in[1];    // [512,256,1]
  const float* Wih = (const float*)d_in[2];   // [768,128]
  const float* Whh = (const float*)d_in[3];   // [768,256]
  const float* bih = (const float*)d_in[4];   // [768]
  const float* bhh = (const float*)d_in[5];   // [768]
  const float* Wdec = (const float*)d_in[6];  // [1,256]
  const float* bdec = (const float*)d_in[7];  // [1]
  float* out = (float*)d_out;

  char* ws = (char*)d_ws;
  char* Wq = ws;                          // 196608 B
  char* wdq = ws + 196608;                // 512 B (256 used)
  float* h_ws = (float*)(ws + 197120);    // 262144 B
  __bf16* Wihb = (__bf16*)(ws + 459264);  // 196608 B
  char* dyn = ws + 655872;
  const size_t per_step = (size_t)393216 + 65536;  // gi + xb per time step
  const size_t pad = 2 * 393216;                   // gi prefetch pad
  size_t avail = ws_size > 655872 + pad ? ws_size - 655872 - pad : per_step;
  int Tc = (int)(avail / per_step);
  if (Tc < 1) Tc = 1;
  if (Tc > 511) Tc = 511;
  __bf16* xb = (__bf16*)dyn;                    // Tc*65536 B
  u32* gi = (u32*)(dyn + (size_t)Tc * 65536);   // (Tc+2)*393216 B

  for (int t0 = 0; t0 < 511; t0 += Tc) {
    const int tc = (511 - t0 < Tc) ? (511 - t0) : Tc;
    xconv_kernel<<<tc * 16, 256, 0, stream>>>(x + (size_t)t0 * 256 * 128, xb,
                                              Whh, Wdec, Wih, Wq, wdq, Wihb,
                                              h_ws, out, t0 == 0 ? 1 : 0);
    gemm1_kernel<<<dim3(6, tc * 2), 256, 0, stream>>>(xb, Wihb, bih, bhh, gi);
    rec_kernel<<<64, 1024, 0, stream>>>(Wq, wdq, gi, gt, bdec, bhh, h_ws, out,
                                        t0, tc);
  }
}